// Round 11
// baseline (98.290 us; speedup 1.0000x reference)
//
#include <hip/hip_runtime.h>

typedef __bf16 bf16;
typedef __bf16 bf16x8 __attribute__((ext_vector_type(8)));
typedef __bf16 bf16x2 __attribute__((ext_vector_type(2)));
typedef float f32x4 __attribute__((ext_vector_type(4)));

#define BS 64
#define CI 64
#define LEN 4096
#define CO 128
#define KS 7
#define NK 4
#define HID 16
#define TEMP 30.0f

#define KTOT 448            // CI*KS
#define WROW 456            // padded wagg row (elems)
#define WBAT (CO * WROW)    // 58368 elems per batch
#define LTILE 128
#define TPB 8               // L-tiles per conv block (1024 l)
#define XB_ROWS 4112        // 8 guard + 4096 + 8 guard
#define XB_ELE (XB_ROWS * 64)

// direct global->LDS DMA, 16B per lane (CK-style addrspace casts)
__device__ __forceinline__ void gl_lds16(const void* g, void* l) {
    auto gp = reinterpret_cast<const __attribute__((address_space(1))) unsigned int*>(
        reinterpret_cast<unsigned long long>(g));
    auto lp = reinterpret_cast<__attribute__((address_space(3))) unsigned int*>(
        reinterpret_cast<unsigned long long>(l));
    __builtin_amdgcn_global_load_lds(gp, lp, 16, 0, 0);
}

// ---------------- transpose + pool partials ----------------
// xbf[b][gl][i]: gl = l + 8, 64 bf16 per row (128 B), chunk c at byte 16*(c^(gl&7)).
// part[b][lt][i] = sum over this block's 512 l.
__global__ __launch_bounds__(256) void trans_kernel(const float* __restrict__ x,
                                                    bf16* __restrict__ xbf,
                                                    float* __restrict__ part) {
    int bid = blockIdx.x;
    int b = bid >> 3, lt = bid & 7;
    int t = threadIdx.x;
    int si = t >> 2, sf = t & 3;
    __shared__ __align__(16) bf16 lds_t[128 * 72];
    __shared__ float lds_red[64 * 4];

    const float* xb = x + (size_t)b * CI * LEN;
    bf16* xo = xbf + (size_t)b * XB_ELE;
    float psum = 0.f;

    for (int st = 0; st < 4; ++st) {
        int ls = lt * 512 + st * 128;
        float4 v[8];
#pragma unroll
        for (int j = 0; j < 8; ++j)
            v[j] = *(const float4*)(xb + (size_t)si * LEN + ls + 4 * (sf + 4 * j));
#pragma unroll
        for (int j = 0; j < 8; ++j) {
            psum += (v[j].x + v[j].y) + (v[j].z + v[j].w);
#pragma unroll
            for (int e = 0; e < 4; ++e)
                lds_t[(4 * (sf + 4 * j) + e) * 72 + si] = (bf16)((&v[j].x)[e]);
        }
        __syncthreads();
        int row = t >> 4, l16 = t & 15;
#pragma unroll
        for (int pass = 0; pass < 8; ++pass) {
            int r = pass * 16 + row;
            int gl = ls + r + 8;
            uint2 d = *(const uint2*)(lds_t + r * 72 + l16 * 4);
            int c = l16 >> 1;
            int sw = c ^ (gl & 7);
            *(uint2*)((char*)xo + (size_t)gl * 128 + sw * 16 + (l16 & 1) * 8) = d;
        }
        __syncthreads();
    }

    lds_red[si * 4 + sf] = psum;
    __syncthreads();
    if (t < 64)
        part[((size_t)b * 8 + lt) * 64 + t] =
            lds_red[t * 4] + lds_red[t * 4 + 1] + lds_red[t * 4 + 2] + lds_red[t * 4 + 3];

    // zero guard rows (plain zeros; swizzle of zeros is zeros)
    if (lt == 0 && t < 128) *(uint2*)((char*)xo + t * 8) = make_uint2(0u, 0u);
    if (lt == 7 && t < 128) *(uint2*)((char*)xo + (size_t)4104 * 128 + t * 8) = make_uint2(0u, 0u);
}

// ---------------- aggw (+ attention recompute from partials) ----------------
__global__ void aggw_kernel(const float* __restrict__ part,
                            const float* __restrict__ w1,
                            const float* __restrict__ w2,
                            const float* __restrict__ weight,
                            float* __restrict__ att_g,
                            bf16* __restrict__ wagg) {
    int o = blockIdx.x >> 1;
    int bh = blockIdx.x & 1;
    int t = threadIdx.x;
    __shared__ float p[32 * 64];
    __shared__ float hsh[32 * 16];
    __shared__ float att_s[32][4];
    __shared__ float lw[4 * KTOT];

    const float* wo = weight + (size_t)o * KTOT;
    for (int idx = t; idx < 4 * KTOT; idx += 256) {
        int bank = idx / KTOT;
        int r = idx - bank * KTOT;
        lw[idx] = wo[(size_t)bank * (CO * KTOT) + r];
    }
    for (int idx = t; idx < 32 * 64; idx += 256) {
        int bb = idx >> 6, i = idx & 63;
        const float* pp = part + ((size_t)(bh * 32 + bb) * 8) * 64 + i;
        float s = 0.f;
#pragma unroll
        for (int j = 0; j < 8; ++j) s += pp[j * 64];
        p[idx] = s * (1.0f / LEN);
    }
    __syncthreads();

    {   // hidden: 32 b x 16 h, 2 per thread
        int bb = t >> 3, h2 = (t & 7) * 2;
#pragma unroll
        for (int u = 0; u < 2; ++u) {
            int hh = h2 + u;
            float s = 0.f;
            for (int i = 0; i < 64; ++i) s += p[bb * 64 + i] * w1[hh * 64 + i];
            hsh[bb * 16 + hh] = fmaxf(s, 0.f);
        }
    }
    __syncthreads();
    if (t < 32) {
        float lg[NK], m = -1e30f;
#pragma unroll
        for (int k = 0; k < NK; ++k) {
            float s = 0.f;
            for (int j = 0; j < HID; ++j) s += hsh[t * 16 + j] * w2[k * HID + j];
            lg[k] = s * (1.0f / TEMP);
            m = fmaxf(m, lg[k]);
        }
        float e[NK], tot = 0.f;
#pragma unroll
        for (int k = 0; k < NK; ++k) { e[k] = expf(lg[k] - m); tot += e[k]; }
        float inv = 1.0f / tot;
#pragma unroll
        for (int k = 0; k < NK; ++k) {
            att_s[t][k] = e[k] * inv;
            if (blockIdx.x < 2) att_g[(bh * 32 + t) * NK + k] = e[k] * inv;
        }
    }
    __syncthreads();

    if (t < 224) {                            // kout pair (2t, 2t+1), kout = f*64+i
        float w8[8];
#pragma unroll
        for (int j = 0; j < 2; ++j) {
            int kout = 2 * t + j;
            int i = kout & 63, f = kout >> 6;
#pragma unroll
            for (int bank = 0; bank < 4; ++bank)
                w8[j * 4 + bank] = lw[bank * KTOT + i * KS + f];
        }
        for (int bb = 0; bb < 32; ++bb) {
            int b = bh * 32 + bb;
            float a0 = att_s[bb][0], a1 = att_s[bb][1];
            float a2 = att_s[bb][2], a3 = att_s[bb][3];
            float v0 = a0 * w8[0] + a1 * w8[1] + a2 * w8[2] + a3 * w8[3];
            float v1 = a0 * w8[4] + a1 * w8[5] + a2 * w8[6] + a3 * w8[7];
            bf16x2 pk; pk[0] = (bf16)v0; pk[1] = (bf16)v1;
            *(bf16x2*)(wagg + (size_t)b * WBAT + o * WROW + 2 * t) = pk;
        }
    }
}

// ---------------- conv: implicit GEMM, DMA-staged swizzled x, W in regs ----------------
__global__ __launch_bounds__(256, 2) void conv_kernel(
    const bf16* __restrict__ xbf,
    const bf16* __restrict__ wagg,
    const float* __restrict__ att_g,
    const float* __restrict__ bias,
    float* __restrict__ out) {
    __shared__ __align__(1024) bf16 lds_x[2][144 * 64];   // 2 x 18432 B
    __shared__ float aggb_l[CO];

    int nwg = gridDim.x;                               // 512 (mult of 8)
    int bid = blockIdx.x;
    int logical = (bid & 7) * (nwg >> 3) + (bid >> 3); // XCD-chunked swizzle (T1)
    int b = logical >> 3;
    int rem = logical & 7;
    int oh = rem >> 2, lsp = rem & 3;

    int t = threadIdx.x;
    int lane = t & 63, wid = t >> 6;
    int ln = lane & 15, g = lane >> 4;
    int wm = wid >> 1, wn = wid & 1;                   // wave tile: 32 o x 64 l

    if (t < CO) {
        float a0 = att_g[b * NK + 0], a1 = att_g[b * NK + 1];
        float a2 = att_g[b * NK + 2], a3 = att_g[b * NK + 3];
        aggb_l[t] = a0 * bias[0 * CO + t] + a1 * bias[1 * CO + t] +
                    a2 * bias[2 * CO + t] + a3 * bias[3 * CO + t];
    }

    // A-fragments (W) into registers, once per 1024 l
    const bf16* wgb = wagg + (size_t)b * WBAT
                    + (size_t)(oh * 64 + wm * 32 + ln) * WROW + g * 8;
    bf16x8 av[2][14];
#pragma unroll
    for (int mf = 0; mf < 2; ++mf)
#pragma unroll
        for (int kk = 0; kk < 14; ++kk)
            av[mf][kk] = *(const bf16x8*)(wgb + mf * 16 * WROW + kk * 32);

    int l0base = lsp * (LTILE * TPB);
    const bf16* xb = xbf + (size_t)b * XB_ELE;

    auto stage = [&](int buf, int l0) {
        // stage physical rows gl = l0 .. l0+143 (l = l0-8 .. l0+135), contiguous 18432 B
        const char* src = (const char*)xb + (size_t)l0 * 128 + lane * 16;
        char* dst = (char*)lds_x[buf];
        for (int c = wid; c < 18; c += 4)
            gl_lds16(src + c * 1024, dst + c * 1024);
    };

    stage(0, l0base);
    __syncthreads();   // compiler drains vmcnt before barrier -> staging complete

    // bias + output row offsets: o = oh*64 + wm*32 + mf*16 + g*4 + r
    float bias_r[2][4];
    int orow_off[2][4];
#pragma unroll
    for (int mf = 0; mf < 2; ++mf)
#pragma unroll
        for (int r = 0; r < 4; ++r) {
            int o = oh * 64 + wm * 32 + mf * 16 + g * 4 + r;
            bias_r[mf][r] = aggb_l[o];
            orow_off[mf][r] = (b * CO + o) * LEN;
        }

    int prow = wn * 64 + ln + 5;    // LDS row for nf=0, f=0

    for (int tl = 0; tl < TPB; ++tl) {
        int l0 = l0base + tl * LTILE;
        if (tl + 1 < TPB) stage((tl + 1) & 1, l0 + LTILE);   // DMA into other buffer

        f32x4 acc[2][4];
#pragma unroll
        for (int mf = 0; mf < 2; ++mf)
#pragma unroll
            for (int nf = 0; nf < 4; ++nf)
                acc[mf][nf] = (f32x4){0.f, 0.f, 0.f, 0.f};

        const char* lb = (const char*)lds_x[tl & 1];

#pragma unroll
        for (int kk = 0; kk < 14; ++kk) {
            int f = kk >> 1;
            int key = (prow + f) & 7;                 // = row&7 for all nf (nf*16 = 0 mod 8)
            int swz = (((kk & 1) * 4 + g) ^ key) * 16; // swizzled 16B chunk within row
            bf16x8 bv[4];
#pragma unroll
            for (int nf = 0; nf < 4; ++nf)
                bv[nf] = *(const bf16x8*)(lb + (prow + nf * 16 + f) * 128 + swz);
#pragma unroll
            for (int mf = 0; mf < 2; ++mf)
#pragma unroll
                for (int nf = 0; nf < 4; ++nf)
                    acc[mf][nf] = __builtin_amdgcn_mfma_f32_16x16x32_bf16(
                        av[mf][kk], bv[nf], acc[mf][nf], 0, 0, 0);
        }

        if (tl + 1 < TPB) __syncthreads();   // drains staging DMA; stores overlap next K-loop

#pragma unroll
        for (int mf = 0; mf < 2; ++mf)
#pragma unroll
            for (int nf = 0; nf < 4; ++nf) {
                int l = l0 + wn * 64 + nf * 16 + ln;
#pragma unroll
                for (int r = 0; r < 4; ++r)
                    out[(size_t)orow_off[mf][r] + l] = acc[mf][nf][r] + bias_r[mf][r];
            }
    }
}

extern "C" void kernel_launch(void* const* d_in, const int* in_sizes, int n_in,
                              void* d_out, int out_size, void* d_ws, size_t ws_size,
                              hipStream_t stream) {
    const float* x  = (const float*)d_in[0];
    const float* w1 = (const float*)d_in[1];
    const float* w2 = (const float*)d_in[2];
    const float* wt = (const float*)d_in[3];
    const float* bs = (const float*)d_in[4];
    float* out = (float*)d_out;

    bf16* xbf    = (bf16*)d_ws;                                        // 33,685,504 B
    bf16* wagg   = (bf16*)((char*)d_ws + (size_t)BS * XB_ELE * 2);     // 7,471,104 B
    float* part  = (float*)((char*)wagg + (size_t)BS * WBAT * 2);      // 131,072 B
    float* att_g = part + BS * 8 * 64;                                 // 1,024 B

    trans_kernel<<<BS * 8, 256, 0, stream>>>(x, xbf, part);
    aggw_kernel<<<CO * 2, 256, 0, stream>>>(part, w1, w2, wt, att_g, wagg);
    conv_kernel<<<BS * 8, 256, 0, stream>>>(xbf, wagg, att_g, bs, out);
    // MEASUREMENT: second, idempotent conv launch. dur_us - 66.1 ≈ conv duration.
    conv_kernel<<<BS * 8, 256, 0, stream>>>(xbf, wagg, att_g, bs, out);
}

// Round 12
// 66.849 us; speedup vs baseline: 1.4703x; 1.4703x over previous
//
#include <hip/hip_runtime.h>

typedef __bf16 bf16;
typedef __bf16 bf16x8 __attribute__((ext_vector_type(8)));
typedef __bf16 bf16x2 __attribute__((ext_vector_type(2)));
typedef float f32x4 __attribute__((ext_vector_type(4)));

#define BS 64
#define CI 64
#define LEN 4096
#define CO 128
#define KS 7
#define NK 4
#define HID 16
#define TEMP 30.0f

#define KTOT 448            // CI*KS
#define WROW 456            // padded wagg row (elems)
#define WBAT (CO * WROW)    // 58368 elems per batch
#define LTILE 128
#define TPB 8               // L-tiles per conv block (1024 l)
#define XB_ROWS 4112        // 8 guard + 4096 + 8 guard
#define XB_ELE (XB_ROWS * 64)
#define NPART 16            // pool partials per batch

// direct global->LDS DMA, 16B per lane (CK-style addrspace casts)
__device__ __forceinline__ void gl_lds16(const void* g, void* l) {
    auto gp = reinterpret_cast<const __attribute__((address_space(1))) unsigned int*>(
        reinterpret_cast<unsigned long long>(g));
    auto lp = reinterpret_cast<__attribute__((address_space(3))) unsigned int*>(
        reinterpret_cast<unsigned long long>(l));
    __builtin_amdgcn_global_load_lds(gp, lp, 16, 0, 0);
}

// ---------------- transpose + pool partials (v2: 1024 blocks, T14, wide stores) ----
// xbf[b][gl][i]: gl = l + 8, 64 bf16 per row (128 B), 16B chunk c at byte 16*(c^(gl&7)).
// part[b][lt][i] = sum over this block's 256 l.
__global__ __launch_bounds__(256) void trans_kernel(const float* __restrict__ x,
                                                    bf16* __restrict__ xbf,
                                                    float* __restrict__ part) {
    int bid = blockIdx.x;
    int b = bid >> 4, lt = bid & 15;
    int t = threadIdx.x;
    int si = t >> 2, sf = t & 3;
    __shared__ __align__(16) bf16 lds_t[128 * 72];
    __shared__ float lds_red[64 * 4];

    const float* xb = x + (size_t)b * CI * LEN;
    bf16* xo = xbf + (size_t)b * XB_ELE;
    float psum = 0.f;
    int ls0 = lt * 256;

    // issue BOTH stages' global loads up front (T14): stage-1 latency hides
    // under stage-0's LDS transpose + store phase.
    float4 v0[8], v1[8];
#pragma unroll
    for (int j = 0; j < 8; ++j)
        v0[j] = *(const float4*)(xb + (size_t)si * LEN + ls0 + 4 * (sf + 4 * j));
#pragma unroll
    for (int j = 0; j < 8; ++j)
        v1[j] = *(const float4*)(xb + (size_t)si * LEN + ls0 + 128 + 4 * (sf + 4 * j));

#pragma unroll
    for (int st = 0; st < 2; ++st) {
        const float4* v = st ? v1 : v0;
        int ls = ls0 + st * 128;
#pragma unroll
        for (int j = 0; j < 8; ++j) {
            float4 vv = v[j];
            psum += (vv.x + vv.y) + (vv.z + vv.w);
#pragma unroll
            for (int e = 0; e < 4; ++e)
                lds_t[(4 * (sf + 4 * j) + e) * 72 + si] = (bf16)((&vv.x)[e]);
        }
        __syncthreads();
        // read back b128, store full 128B lines (8 lanes x 16B per row)
        int row = t >> 3, l8 = t & 7;
#pragma unroll
        for (int pass = 0; pass < 4; ++pass) {
            int r = pass * 32 + row;
            int gl = ls + r + 8;
            uint4 d = *(const uint4*)((const char*)lds_t + r * 144 + l8 * 16);
            int sw = l8 ^ (gl & 7);
            *(uint4*)((char*)xo + (size_t)gl * 128 + sw * 16) = d;
        }
        if (st == 0) __syncthreads();   // lds_t reused by stage 1
    }

    lds_red[si * 4 + sf] = psum;
    __syncthreads();
    if (t < 64)
        part[((size_t)b * NPART + lt) * 64 + t] =
            lds_red[t * 4] + lds_red[t * 4 + 1] + lds_red[t * 4 + 2] + lds_red[t * 4 + 3];

    // zero guard rows (swizzle of zeros is zeros)
    if (lt == 0 && t < 128) *(uint2*)((char*)xo + t * 8) = make_uint2(0u, 0u);
    if (lt == 15 && t < 128) *(uint2*)((char*)xo + (size_t)4104 * 128 + t * 8) = make_uint2(0u, 0u);
}

// ---------------- aggw (+ attention recompute from partials) ----------------
__global__ void aggw_kernel(const float* __restrict__ part,
                            const float* __restrict__ w1,
                            const float* __restrict__ w2,
                            const float* __restrict__ weight,
                            float* __restrict__ att_g,
                            bf16* __restrict__ wagg) {
    int o = blockIdx.x >> 1;
    int bh = blockIdx.x & 1;
    int t = threadIdx.x;
    __shared__ float p[32 * 64];
    __shared__ float hsh[32 * 16];
    __shared__ float att_s[32][4];
    __shared__ float lw[4 * KTOT];

    const float* wo = weight + (size_t)o * KTOT;
    for (int idx = t; idx < 4 * KTOT; idx += 256) {
        int bank = idx / KTOT;
        int r = idx - bank * KTOT;
        lw[idx] = wo[(size_t)bank * (CO * KTOT) + r];
    }
    for (int idx = t; idx < 32 * 64; idx += 256) {
        int bb = idx >> 6, i = idx & 63;
        const float* pp = part + ((size_t)(bh * 32 + bb) * NPART) * 64 + i;
        float s = 0.f;
#pragma unroll
        for (int j = 0; j < NPART; ++j) s += pp[j * 64];
        p[idx] = s * (1.0f / LEN);
    }
    __syncthreads();

    {   // hidden: 32 b x 16 h, 2 per thread
        int bb = t >> 3, h2 = (t & 7) * 2;
#pragma unroll
        for (int u = 0; u < 2; ++u) {
            int hh = h2 + u;
            float s = 0.f;
            for (int i = 0; i < 64; ++i) s += p[bb * 64 + i] * w1[hh * 64 + i];
            hsh[bb * 16 + hh] = fmaxf(s, 0.f);
        }
    }
    __syncthreads();
    if (t < 32) {
        float lg[NK], m = -1e30f;
#pragma unroll
        for (int k = 0; k < NK; ++k) {
            float s = 0.f;
            for (int j = 0; j < HID; ++j) s += hsh[t * 16 + j] * w2[k * HID + j];
            lg[k] = s * (1.0f / TEMP);
            m = fmaxf(m, lg[k]);
        }
        float e[NK], tot = 0.f;
#pragma unroll
        for (int k = 0; k < NK; ++k) { e[k] = expf(lg[k] - m); tot += e[k]; }
        float inv = 1.0f / tot;
#pragma unroll
        for (int k = 0; k < NK; ++k) {
            att_s[t][k] = e[k] * inv;
            if (blockIdx.x < 2) att_g[(bh * 32 + t) * NK + k] = e[k] * inv;
        }
    }
    __syncthreads();

    if (t < 224) {                            // kout pair (2t, 2t+1), kout = f*64+i
        float w8[8];
#pragma unroll
        for (int j = 0; j < 2; ++j) {
            int kout = 2 * t + j;
            int i = kout & 63, f = kout >> 6;
#pragma unroll
            for (int bank = 0; bank < 4; ++bank)
                w8[j * 4 + bank] = lw[bank * KTOT + i * KS + f];
        }
        for (int bb = 0; bb < 32; ++bb) {
            int b = bh * 32 + bb;
            float a0 = att_s[bb][0], a1 = att_s[bb][1];
            float a2 = att_s[bb][2], a3 = att_s[bb][3];
            float v0 = a0 * w8[0] + a1 * w8[1] + a2 * w8[2] + a3 * w8[3];
            float v1 = a0 * w8[4] + a1 * w8[5] + a2 * w8[6] + a3 * w8[7];
            bf16x2 pk; pk[0] = (bf16)v0; pk[1] = (bf16)v1;
            *(bf16x2*)(wagg + (size_t)b * WBAT + o * WROW + 2 * t) = pk;
        }
    }
}

// ---------------- conv: implicit GEMM, DMA-staged swizzled x, W in regs ----------------
__global__ __launch_bounds__(256, 2) void conv_kernel(
    const bf16* __restrict__ xbf,
    const bf16* __restrict__ wagg,
    const float* __restrict__ att_g,
    const float* __restrict__ bias,
    float* __restrict__ out) {
    __shared__ __align__(1024) bf16 lds_x[2][144 * 64];   // 2 x 18432 B
    __shared__ float aggb_l[CO];

    int nwg = gridDim.x;                               // 512 (mult of 8)
    int bid = blockIdx.x;
    int logical = (bid & 7) * (nwg >> 3) + (bid >> 3); // XCD-chunked swizzle (T1)
    int b = logical >> 3;
    int rem = logical & 7;
    int oh = rem >> 2, lsp = rem & 3;

    int t = threadIdx.x;
    int lane = t & 63, wid = t >> 6;
    int ln = lane & 15, g = lane >> 4;
    int wm = wid >> 1, wn = wid & 1;                   // wave tile: 32 o x 64 l

    if (t < CO) {
        float a0 = att_g[b * NK + 0], a1 = att_g[b * NK + 1];
        float a2 = att_g[b * NK + 2], a3 = att_g[b * NK + 3];
        aggb_l[t] = a0 * bias[0 * CO + t] + a1 * bias[1 * CO + t] +
                    a2 * bias[2 * CO + t] + a3 * bias[3 * CO + t];
    }

    // A-fragments (W) into registers, once per 1024 l
    const bf16* wgb = wagg + (size_t)b * WBAT
                    + (size_t)(oh * 64 + wm * 32 + ln) * WROW + g * 8;
    bf16x8 av[2][14];
#pragma unroll
    for (int mf = 0; mf < 2; ++mf)
#pragma unroll
        for (int kk = 0; kk < 14; ++kk)
            av[mf][kk] = *(const bf16x8*)(wgb + mf * 16 * WROW + kk * 32);

    int l0base = lsp * (LTILE * TPB);
    const bf16* xb = xbf + (size_t)b * XB_ELE;

    auto stage = [&](int buf, int l0) {
        // stage physical rows gl = l0 .. l0+143 (l = l0-8 .. l0+135), contiguous 18432 B
        const char* src = (const char*)xb + (size_t)l0 * 128 + lane * 16;
        char* dst = (char*)lds_x[buf];
        for (int c = wid; c < 18; c += 4)
            gl_lds16(src + c * 1024, dst + c * 1024);
    };

    stage(0, l0base);
    __syncthreads();   // compiler drains vmcnt before barrier -> staging complete

    // bias + output row offsets: o = oh*64 + wm*32 + mf*16 + g*4 + r
    float bias_r[2][4];
    int orow_off[2][4];
#pragma unroll
    for (int mf = 0; mf < 2; ++mf)
#pragma unroll
        for (int r = 0; r < 4; ++r) {
            int o = oh * 64 + wm * 32 + mf * 16 + g * 4 + r;
            bias_r[mf][r] = aggb_l[o];
            orow_off[mf][r] = (b * CO + o) * LEN;
        }

    int prow = wn * 64 + ln + 5;    // LDS row for nf=0, f=0

    for (int tl = 0; tl < TPB; ++tl) {
        int l0 = l0base + tl * LTILE;
        if (tl + 1 < TPB) stage((tl + 1) & 1, l0 + LTILE);   // DMA into other buffer

        f32x4 acc[2][4];
#pragma unroll
        for (int mf = 0; mf < 2; ++mf)
#pragma unroll
            for (int nf = 0; nf < 4; ++nf)
                acc[mf][nf] = (f32x4){0.f, 0.f, 0.f, 0.f};

        const char* lb = (const char*)lds_x[tl & 1];

#pragma unroll
        for (int kk = 0; kk < 14; ++kk) {
            int f = kk >> 1;
            int key = (prow + f) & 7;                 // = row&7 for all nf (nf*16 = 0 mod 8)
            int swz = (((kk & 1) * 4 + g) ^ key) * 16; // swizzled 16B chunk within row
            bf16x8 bv[4];
#pragma unroll
            for (int nf = 0; nf < 4; ++nf)
                bv[nf] = *(const bf16x8*)(lb + (prow + nf * 16 + f) * 128 + swz);
#pragma unroll
            for (int mf = 0; mf < 2; ++mf)
#pragma unroll
                for (int nf = 0; nf < 4; ++nf)
                    acc[mf][nf] = __builtin_amdgcn_mfma_f32_16x16x32_bf16(
                        av[mf][kk], bv[nf], acc[mf][nf], 0, 0, 0);
        }

        if (tl + 1 < TPB) __syncthreads();   // drains staging DMA; stores overlap next K-loop

#pragma unroll
        for (int mf = 0; mf < 2; ++mf)
#pragma unroll
            for (int nf = 0; nf < 4; ++nf) {
                int l = l0 + wn * 64 + nf * 16 + ln;
#pragma unroll
                for (int r = 0; r < 4; ++r)
                    out[(size_t)orow_off[mf][r] + l] = acc[mf][nf][r] + bias_r[mf][r];
            }
    }
}

extern "C" void kernel_launch(void* const* d_in, const int* in_sizes, int n_in,
                              void* d_out, int out_size, void* d_ws, size_t ws_size,
                              hipStream_t stream) {
    const float* x  = (const float*)d_in[0];
    const float* w1 = (const float*)d_in[1];
    const float* w2 = (const float*)d_in[2];
    const float* wt = (const float*)d_in[3];
    const float* bs = (const float*)d_in[4];
    float* out = (float*)d_out;

    bf16* xbf    = (bf16*)d_ws;                                        // 33,685,504 B
    bf16* wagg   = (bf16*)((char*)d_ws + (size_t)BS * XB_ELE * 2);     // 7,471,104 B
    float* part  = (float*)((char*)wagg + (size_t)BS * WBAT * 2);      // 262,144 B
    float* att_g = part + BS * NPART * 64;                             // 1,024 B

    trans_kernel<<<BS * 16, 256, 0, stream>>>(x, xbf, part);
    aggw_kernel<<<CO * 2, 256, 0, stream>>>(part, w1, w2, wt, att_g, wagg);
    conv_kernel<<<BS * 8, 256, 0, stream>>>(xbf, wagg, att_g, bs, out);
}